// Round 1
// baseline (810.380 us; speedup 1.0000x reference)
//
#include <hip/hip_runtime.h>

// Gray-Scott residual kernel.
// Input tensor: (T=50, C=2, Y=100, X=100, Z=100) float32, strides:
//   t: 2,000,000  c: 1,000,000  y: 10,000  x: 100  z: 1
// Output: f_u (48,96,96,96) then f_v (48,96,96,96), concatenated flat.
//
// Separable 13-point laplacian: s = [-1/12, 4/3, -5/2, 4/3, -1/12] along each
// axis; center coefficient = 3 * (-5/2) = -7.5.

#define N_OUT (48 * 96 * 96 * 96)   // 42,467,328 per channel

__global__ __launch_bounds__(256) void grayscott_kernel(
    const float* __restrict__ in, float* __restrict__ out) {
  const int idx = blockIdx.x * 256 + threadIdx.x;  // grid sized exactly

  // idx = ((t*96 + oy)*96 + ox)*96 + oz  -- matches output flat layout.
  int oz = idx % 96;
  int tmp = idx / 96;
  int ox = tmp % 96;
  tmp /= 96;
  int oy = tmp % 96;
  int t = tmp / 96;

  const int iz = oz + 2;
  const int ix = ox + 2;
  const int iy = oy + 2;

  // All offsets fit in signed 32-bit (max byte offset ~400MB < 2^31).
  const int base = t * 2000000 + iy * 10000 + ix * 100 + iz;
  const float* __restrict__ u = in + base;            // channel 0
  const float* __restrict__ v = in + base + 1000000;  // channel 1

  const float c0 = -1.0f / 12.0f;  // taps at +/-2
  const float c1 = 4.0f / 3.0f;    // taps at +/-1
  const float cc = -7.5f;          // combined center
  const float inv_dx2 = 0.2304f;   // 1/DX^2, DX = 100/48

  const float uc = u[0];
  const float vc = v[0];

  float lap_u = cc * uc
      + c1 * (u[1] + u[-1] + u[100] + u[-100] + u[10000] + u[-10000])
      + c0 * (u[2] + u[-2] + u[200] + u[-200] + u[20000] + u[-20000]);
  float lap_v = cc * vc
      + c1 * (v[1] + v[-1] + v[100] + v[-100] + v[10000] + v[-10000])
      + c0 * (v[2] + v[-2] + v[200] + v[-200] + v[20000] + v[-20000]);

  const float un = u[2000000];  // t+1, same spatial point
  const float vn = v[2000000];

  lap_u *= inv_dx2;
  lap_v *= inv_dx2;

  const float uv2 = uc * vc * vc;
  // f_u = DU*lap_u - u*v^2 + FF*(1-u) - (u_next - u)/DT     (1/DT = 2)
  const float f_u = 0.2f * lap_u - uv2 + 0.025f * (1.0f - uc) - (un - uc) * 2.0f;
  // f_v = DV*lap_v + u*v^2 - (FF+KK)*v - (v_next - v)/DT
  const float f_v = 0.1f * lap_v + uv2 - 0.08f * vc - (vn - vc) * 2.0f;

  out[idx] = f_u;
  out[idx + N_OUT] = f_v;
}

extern "C" void kernel_launch(void* const* d_in, const int* in_sizes, int n_in,
                              void* d_out, int out_size, void* d_ws, size_t ws_size,
                              hipStream_t stream) {
  const float* in = (const float*)d_in[0];
  float* out = (float*)d_out;
  // N_OUT / 256 = 165,888 blocks exactly (42,467,328 % 256 == 0).
  const int nblocks = N_OUT / 256;
  grayscott_kernel<<<dim3(nblocks), dim3(256), 0, stream>>>(in, out);
}